// Round 9
// baseline (12.564 us; speedup 1.0000x reference)
//
#include <hip/hip_runtime.h>

typedef float2 cpx;

__device__ __forceinline__ cpx cmul(cpx a, cpx b){
  return make_float2(a.x*b.x - a.y*b.y, a.x*b.y + a.y*b.x);
}
__device__ __forceinline__ cpx cadd(cpx a, cpx b){ return make_float2(a.x+b.x, a.y+b.y); }
__device__ __forceinline__ cpx czero(){ return make_float2(0.f,0.f); }

// 1=RX, 2=RY, 3=RZ (half-angle ch, sh)
__device__ __forceinline__ cpx rot_e(int p, int i, int j, float ch, float sh){
  if (p==1){ if (i==j) return make_float2(ch,0.f); return make_float2(0.f,-sh); }
  else if (p==2){ if (i==j) return make_float2(ch,0.f); return make_float2(i==1?sh:-sh, 0.f); }
  else { if (i!=j) return czero(); return make_float2(ch, i==0?-sh:sh); }
}

// A_p = B_p^2 : p=3 -> I ; p=1 (X, RY(-90)) -> [[0,1],[-1,0]] ; p=2 (Y, RX(+90)) -> [[0,-i],[-i,0]]
__device__ __forceinline__ cpx Ae(int p, int i, int j){
  if (p==3) return make_float2(i==j?1.f:0.f, 0.f);
  if (i==j) return czero();
  if (p==1) return make_float2(i==0?1.f:-1.f, 0.f);
  return make_float2(0.f,-1.f);
}

// Entry (r,c) of gate i (1..15). pa=i>>2, pb=i&3 (0=I,1=X,2=Y,3=Z).
// Composite (both non-I): G = ch*(Apa⊗Apb) - i*sh*(Z⊗Z)   [B·Z·B = Z exactly;
// derived from the faithful P*diag*P construction via kron mixed-product].
__device__ __forceinline__ cpx gate_entry(int i, int r, int c, float ch, float sh){
  int pa = i>>2, pb = i&3;
  if (pa==0 || pb==0){
    int p = pa ? pa : pb;
    if (pa) return ((r&1)==(c&1))   ? rot_e(p, r>>1, c>>1, ch, sh) : czero();
    else    return ((r>>1)==(c>>1)) ? rot_e(p, r&1,  c&1,  ch, sh) : czero();
  }
  cpx a = cmul(Ae(pa, r>>1, c>>1), Ae(pb, r&1, c&1));
  cpx g = make_float2(ch*a.x, ch*a.y);
  if (r==c){ float zz = (r==0 || r==3) ? 1.f : -1.f; g.y -= sh*zz; }
  return g;
}

// In-wave LDS sync: DS ops complete per-wave; drain lgkmcnt + block compiler motion.
#define WSYNC() do { __builtin_amdgcn_wave_barrier(); \
  asm volatile("s_waitcnt lgkmcnt(0)" ::: "memory"); \
  __builtin_amdgcn_wave_barrier(); } while(0)

// Select 2x2 matrix T^bb into named regs (no runtime-indexed arrays -> stays in VGPRs)
#define SELT(bb, m00,m01,m10,m11) \
  m00 = (bb) ? t100 : t000; m01 = (bb) ? t101 : t001; \
  m10 = (bb) ? t110 : t010; m11 = (bb) ? t111 : t011;

// MPS bond-2: psi(b19..b0) = s(b19)^T T^{b18}...T^{b2} e(b1,b0);
//   T[z][yi][yo] = U[(z<<1)|yo, yi<<1];  e(b1,b0)_y = T[b1][y][b0].
// out(i) = | u4[i>>16] * M4[(i>>12)&15] * M4[(i>>8)&15] * M4[(i>>4)&15] * f4[i&15] |^2
// ZERO block barriers: each wave builds its own private table copy (in-wave
// WSYNC ordering only), then writes its slice. 4x redundant setup is free.
__global__ __launch_bounds__(256) void mps_fused(const float* __restrict__ params,
                                                 float* __restrict__ out){
  __shared__ cpx Gm[4][16][16];   // per-wave: gates 1..15
  __shared__ cpx P[4][8][16];     // pair products, P[7]=G15
  __shared__ cpx Q[4][4][16];     // U = Q3*Q2*Q1*Q0
  __shared__ cpx R[4][2][16];     // R1=Q3*Q2, R0=Q1*Q0
  __shared__ cpx Tl[4][8];        // T[z][yi][yo] at (z<<2)|(yi<<1)|yo
  __shared__ cpx u4[4][16][2];
  __shared__ cpx M4p[4][16][5];   // padded stride 5 -> conflict-free rows
  __shared__ cpx f4p[4][16][3];   // padded stride 3
  const int t = threadIdx.x;
  const int wv = t>>6, l = t&63;

  // ---- A: gates. Lane l (>=4) owns 4 consecutive entries of gate i=l>>2:
  //      ONE sincos pair per lane, closed-form entries. ----
  if (l >= 4){
    int i = l>>2;
    float h = 0.5f*params[i-1];
    float ch = __cosf(h), sh = __sinf(h);
    #pragma unroll
    for (int jj=0; jj<4; ++jj){
      int e = ((l&3)<<2) | jj;
      Gm[wv][i][e] = gate_entry(i, e>>2, e&3, ch, sh);
    }
  }
  WSYNC();

  // ---- B: P[p] = G_{2p+2}*G_{2p+1} (p<7), P[7]=G15 ; jobs j=l, l+64 ----
  #pragma unroll
  for (int jj=0; jj<2; ++jj){
    int j = l + jj*64;
    int p = j>>4, e = j&15, r = e>>2, c = e&3;
    if (p < 7){
      cpx s = czero();
      #pragma unroll
      for (int k=0;k<4;k++) s = cadd(s, cmul(Gm[wv][2*p+2][r*4+k], Gm[wv][2*p+1][k*4+c]));
      P[wv][p][e] = s;
    } else {
      P[wv][7][e] = Gm[wv][15][e];
    }
  }
  WSYNC();

  // ---- C: Q[p] = P[2p+1]*P[2p] ----
  {
    int p = l>>4, e = l&15, r = e>>2, c = e&3;
    cpx s = czero();
    #pragma unroll
    for (int k=0;k<4;k++) s = cadd(s, cmul(P[wv][2*p+1][r*4+k], P[wv][2*p][k*4+c]));
    Q[wv][p][e] = s;
  }
  WSYNC();

  // ---- R: R[p] = Q[2p+1]*Q[2p]  (R1*R0 = U) ----
  if (l < 32){
    int p = l>>4, e = l&15, r = e>>2, c = e&3;
    cpx s = czero();
    #pragma unroll
    for (int k=0;k<4;k++) s = cadd(s, cmul(Q[wv][2*p+1][r*4+k], Q[wv][2*p][k*4+c]));
    R[wv][p][e] = s;
  }
  WSYNC();

  // ---- T: the 8 needed U entries: T[z][yi][yo] = U[(z<<1)|yo, yi<<1] ----
  if (l < 8){
    int z=(l>>2)&1, yi=(l>>1)&1, yo=l&1;
    int a=(z<<1)|yo, b=yi<<1;
    cpx s = czero();
    #pragma unroll
    for (int k=0;k<4;k++) s = cadd(s, cmul(R[wv][1][a*4+k], R[wv][0][k*4+b]));
    Tl[wv][l] = s;
  }
  WSYNC();

  // ---- E: tables from T (named regs + ternary selects only) ----
  if (l < 48){
    cpx t000=Tl[wv][0], t001=Tl[wv][1], t010=Tl[wv][2], t011=Tl[wv][3];
    cpx t100=Tl[wv][4], t101=Tl[wv][5], t110=Tl[wv][6], t111=Tl[wv][7];
    int kind = l>>4, pat = l&15;
    int q3=pat>>3, q2=(pat>>2)&1, q1=(pat>>1)&1, q0=pat&1;
    cpx m00,m01,m10,m11;
    if (kind == 0){
      // u4: s(q3)=row0 of T^{q3}, then x T^{q2}, T^{q1}, T^{q0}
      cpx r0 = q3 ? t100 : t000;
      cpx r1 = q3 ? t101 : t001;
      SELT(q2, m00,m01,m10,m11);
      { cpx n0 = cadd(cmul(r0,m00),cmul(r1,m10)); cpx n1 = cadd(cmul(r0,m01),cmul(r1,m11)); r0=n0; r1=n1; }
      SELT(q1, m00,m01,m10,m11);
      { cpx n0 = cadd(cmul(r0,m00),cmul(r1,m10)); cpx n1 = cadd(cmul(r0,m01),cmul(r1,m11)); r0=n0; r1=n1; }
      SELT(q0, m00,m01,m10,m11);
      { cpx n0 = cadd(cmul(r0,m00),cmul(r1,m10)); cpx n1 = cadd(cmul(r0,m01),cmul(r1,m11)); r0=n0; r1=n1; }
      u4[wv][pat][0]=r0; u4[wv][pat][1]=r1;
    } else if (kind == 1){
      // M4 = T^{q3} T^{q2} T^{q1} T^{q0}
      cpx M00,M01,M10,M11;
      SELT(q3, M00,M01,M10,M11);
      SELT(q2, m00,m01,m10,m11);
      { cpx N00=cadd(cmul(M00,m00),cmul(M01,m10)), N01=cadd(cmul(M00,m01),cmul(M01,m11));
        cpx N10=cadd(cmul(M10,m00),cmul(M11,m10)), N11=cadd(cmul(M10,m01),cmul(M11,m11));
        M00=N00; M01=N01; M10=N10; M11=N11; }
      SELT(q1, m00,m01,m10,m11);
      { cpx N00=cadd(cmul(M00,m00),cmul(M01,m10)), N01=cadd(cmul(M00,m01),cmul(M01,m11));
        cpx N10=cadd(cmul(M10,m00),cmul(M11,m10)), N11=cadd(cmul(M10,m01),cmul(M11,m11));
        M00=N00; M01=N01; M10=N10; M11=N11; }
      SELT(q0, m00,m01,m10,m11);
      { cpx N00=cadd(cmul(M00,m00),cmul(M01,m10)), N01=cadd(cmul(M00,m01),cmul(M01,m11));
        cpx N10=cadd(cmul(M10,m00),cmul(M11,m10)), N11=cadd(cmul(M10,m01),cmul(M11,m11));
        M00=N00; M01=N01; M10=N10; M11=N11; }
      M4p[wv][pat][0]=M00; M4p[wv][pat][1]=M01; M4p[wv][pat][2]=M10; M4p[wv][pat][3]=M11;
    } else {
      // f4: seed e(b1,b0)_y = T[b1][y][b0]; then apply T^{b2}, T^{b3} (col-vec)
      cpx v0 = q1 ? (q0 ? t101 : t100) : (q0 ? t001 : t000);
      cpx v1 = q1 ? (q0 ? t111 : t110) : (q0 ? t011 : t010);
      SELT(q2, m00,m01,m10,m11);
      { cpx n0 = cadd(cmul(m00,v0),cmul(m01,v1)); cpx n1 = cadd(cmul(m10,v0),cmul(m11,v1)); v0=n0; v1=n1; }
      SELT(q3, m00,m01,m10,m11);
      { cpx n0 = cadd(cmul(m00,v0),cmul(m01,v1)); cpx n1 = cadd(cmul(m10,v0),cmul(m11,v1)); v0=n0; v1=n1; }
      f4p[wv][pat][0]=v0; f4p[wv][pat][1]=v1;
    }
  }
  WSYNC();

  // ---- F: combine + coalesced store. i = (bid<<10)|(t<<2)|k ----
  unsigned bid = blockIdx.x;
  cpx r0 = u4[wv][bid>>6][0], r1 = u4[wv][bid>>6][1];
  {
    const cpx* Ma = M4p[wv][(bid>>2)&15u];            // bits 15..12 (block-uniform)
    cpx n0 = cadd(cmul(r0,Ma[0]), cmul(r1,Ma[2]));
    cpx n1 = cadd(cmul(r0,Ma[1]), cmul(r1,Ma[3]));
    r0=n0; r1=n1;
  }
  {
    const cpx* Mb = M4p[wv][((bid&3u)<<2)|(unsigned)wv]; // bits 11..8 (wave-uniform)
    cpx n0 = cadd(cmul(r0,Mb[0]), cmul(r1,Mb[2]));
    cpx n1 = cadd(cmul(r0,Mb[1]), cmul(r1,Mb[3]));
    r0=n0; r1=n1;
  }
  {
    const cpx* Mc = M4p[wv][(l>>2)&15];               // bits 7..4 (per-thread)
    cpx n0 = cadd(cmul(r0,Mc[0]), cmul(r1,Mc[2]));
    cpx n1 = cadd(cmul(r0,Mc[1]), cmul(r1,Mc[3]));
    r0=n0; r1=n1;
  }
  int fb = (l&3)<<2;                                  // bits 3..2 from t, 1..0 = k
  float4 res; cpx y;
  y = cadd(cmul(r0, f4p[wv][fb  ][0]), cmul(r1, f4p[wv][fb  ][1])); res.x = y.x*y.x + y.y*y.y;
  y = cadd(cmul(r0, f4p[wv][fb|1][0]), cmul(r1, f4p[wv][fb|1][1])); res.y = y.x*y.x + y.y*y.y;
  y = cadd(cmul(r0, f4p[wv][fb|2][0]), cmul(r1, f4p[wv][fb|2][1])); res.z = y.x*y.x + y.y*y.y;
  y = cadd(cmul(r0, f4p[wv][fb|3][0]), cmul(r1, f4p[wv][fb|3][1])); res.w = y.x*y.x + y.y*y.y;
  ((float4*)out)[(bid<<8) | (unsigned)t] = res;
}

extern "C" void kernel_launch(void* const* d_in, const int* in_sizes, int n_in,
                              void* d_out, int out_size, void* d_ws, size_t ws_size,
                              hipStream_t stream) {
  const float* params = (const float*)d_in[0];
  mps_fused<<<1024, 256, 0, stream>>>(params, (float*)d_out);
}

// Round 10
// 10.888 us; speedup vs baseline: 1.1539x; 1.1539x over previous
//
#include <hip/hip_runtime.h>

typedef float2 cpx;

__device__ __forceinline__ cpx cmul(cpx a, cpx b){
  return make_float2(a.x*b.x - a.y*b.y, a.x*b.y + a.y*b.x);
}
__device__ __forceinline__ cpx cadd(cpx a, cpx b){ return make_float2(a.x+b.x, a.y+b.y); }
__device__ __forceinline__ cpx czero(){ return make_float2(0.f,0.f); }

// 1=RX, 2=RY, 3=RZ (half-angle ch, sh)
__device__ __forceinline__ cpx rot_e(int p, int i, int j, float ch, float sh){
  if (p==1){ if (i==j) return make_float2(ch,0.f); return make_float2(0.f,-sh); }
  else if (p==2){ if (i==j) return make_float2(ch,0.f); return make_float2(i==1?sh:-sh, 0.f); }
  else { if (i!=j) return czero(); return make_float2(ch, i==0?-sh:sh); }
}

// A_p = B_p^2 : p=3 -> I ; p=1 (X, RY(-90)) -> [[0,1],[-1,0]] ; p=2 (Y, RX(+90)) -> [[0,-i],[-i,0]]
__device__ __forceinline__ cpx Ae(int p, int i, int j){
  if (p==3) return make_float2(i==j?1.f:0.f, 0.f);
  if (i==j) return czero();
  if (p==1) return make_float2(i==0?1.f:-1.f, 0.f);
  return make_float2(0.f,-1.f);
}

// Entry (r,c) of gate i (1..15). pa=i>>2, pb=i&3 (0=I,1=X,2=Y,3=Z).
// Composite (both non-I): G = ch*(Apa⊗Apb) - i*sh*(Z⊗Z)   [B·Z·B = Z exactly;
// derived from the faithful P*diag*P construction via kron mixed-product].
__device__ __forceinline__ cpx gate_entry(int i, int r, int c, float ch, float sh){
  int pa = i>>2, pb = i&3;
  if (pa==0 || pb==0){
    int p = pa ? pa : pb;
    if (pa) return ((r&1)==(c&1))   ? rot_e(p, r>>1, c>>1, ch, sh) : czero();
    else    return ((r>>1)==(c>>1)) ? rot_e(p, r&1,  c&1,  ch, sh) : czero();
  }
  cpx a = cmul(Ae(pa, r>>1, c>>1), Ae(pb, r&1, c&1));
  cpx g = make_float2(ch*a.x, ch*a.y);
  if (r==c){ float zz = (r==0 || r==3) ? 1.f : -1.f; g.y -= sh*zz; }
  return g;
}

// In-wave LDS sync: DS ops complete per-wave; drain lgkmcnt + block compiler motion.
#define WSYNC() do { __builtin_amdgcn_wave_barrier(); \
  asm volatile("s_waitcnt lgkmcnt(0)" ::: "memory"); \
  __builtin_amdgcn_wave_barrier(); } while(0)

// Select 2x2 matrix T^bb into named regs (no runtime-indexed arrays -> stays in VGPRs)
#define SELT(bb, m00,m01,m10,m11) \
  m00 = (bb) ? t100 : t000; m01 = (bb) ? t101 : t001; \
  m10 = (bb) ? t110 : t010; m11 = (bb) ? t111 : t011;

// MPS bond-2: psi(b19..b0) = s(b19)^T T^{b18}...T^{b2} e(b1,b0);
//   T[z][yi][yo] = U[(z<<1)|yo, yi<<1];  e(b1,b0)_y = T[b1][y][b0].
// out(i) = | u4[i>>16] * M4[(i>>12)&15] * M4[(i>>8)&15] * M4[(i>>4)&15] * f4[i&15] |^2
// Structure: wave-0 straight-line {A,B,C,R,T,E} with in-wave WSYNCs only
// (waves 1-3 sleep at the barrier -> 1 active setup wave per SIMD),
// then ONE block barrier, then wide F (combine + coalesced store).
__global__ __launch_bounds__(256) void mps_fused(const float* __restrict__ params,
                                                 float* __restrict__ out){
  __shared__ cpx Gm[16][16];   // gates 1..15
  __shared__ cpx P[8][16];     // pair products, P[7]=G15
  __shared__ cpx Q[4][16];     // U = Q3*Q2*Q1*Q0
  __shared__ cpx R[2][16];     // R1=Q3*Q2, R0=Q1*Q0
  __shared__ cpx Tl[8];        // T[z][yi][yo] at (z<<2)|(yi<<1)|yo
  __shared__ cpx u4[16][2];
  __shared__ cpx M4p[16][5];   // padded stride 5 -> conflict-free rows
  __shared__ cpx f4p[16][3];   // padded stride 3
  const int t = threadIdx.x;

  if (t < 64){
    // ---- A: gates. Lane l>=4 owns 4 consecutive entries of gate i=l>>2:
    //      ONE sincos pair per lane, closed-form entries. (validated in R9) ----
    if (t >= 4){
      int i = t>>2;
      float h = 0.5f*params[i-1];
      float ch = __cosf(h), sh = __sinf(h);
      #pragma unroll
      for (int jj=0; jj<4; ++jj){
        int e = ((t&3)<<2) | jj;
        Gm[i][e] = gate_entry(i, e>>2, e&3, ch, sh);
      }
    }
    WSYNC();

    // ---- B: P[p] = G_{2p+2}*G_{2p+1} (p<7), P[7]=G15 ; jobs j=t, t+64 ----
    #pragma unroll
    for (int jj=0; jj<2; ++jj){
      int j = t + jj*64;
      int p = j>>4, e = j&15, r = e>>2, c = e&3;
      if (p < 7){
        cpx s = czero();
        #pragma unroll
        for (int k=0;k<4;k++) s = cadd(s, cmul(Gm[2*p+2][r*4+k], Gm[2*p+1][k*4+c]));
        P[p][e] = s;
      } else {
        P[7][e] = Gm[15][e];
      }
    }
    WSYNC();

    // ---- C: Q[p] = P[2p+1]*P[2p] ----
    {
      int p = t>>4, e = t&15, r = e>>2, c = e&3;
      cpx s = czero();
      #pragma unroll
      for (int k=0;k<4;k++) s = cadd(s, cmul(P[2*p+1][r*4+k], P[2*p][k*4+c]));
      Q[p][e] = s;
    }
    WSYNC();

    // ---- R: R[p] = Q[2p+1]*Q[2p]  (R1*R0 = U) ----
    if (t < 32){
      int p = t>>4, e = t&15, r = e>>2, c = e&3;
      cpx s = czero();
      #pragma unroll
      for (int k=0;k<4;k++) s = cadd(s, cmul(Q[2*p+1][r*4+k], Q[2*p][k*4+c]));
      R[p][e] = s;
    }
    WSYNC();

    // ---- T: the 8 needed U entries: T[z][yi][yo] = U[(z<<1)|yo, yi<<1] ----
    if (t < 8){
      int z=(t>>2)&1, yi=(t>>1)&1, yo=t&1;
      int a=(z<<1)|yo, b=yi<<1;
      cpx s = czero();
      #pragma unroll
      for (int k=0;k<4;k++) s = cadd(s, cmul(R[1][a*4+k], R[0][k*4+b]));
      Tl[t] = s;
    }
    WSYNC();

    // ---- E: tables from T (named regs + ternary selects only) ----
    if (t < 48){
      cpx t000=Tl[0], t001=Tl[1], t010=Tl[2], t011=Tl[3];
      cpx t100=Tl[4], t101=Tl[5], t110=Tl[6], t111=Tl[7];
      int kind = t>>4, pat = t&15;
      int q3=pat>>3, q2=(pat>>2)&1, q1=(pat>>1)&1, q0=pat&1;
      cpx m00,m01,m10,m11;
      if (kind == 0){
        // u4: s(q3)=row0 of T^{q3}, then x T^{q2}, T^{q1}, T^{q0}
        cpx r0 = q3 ? t100 : t000;
        cpx r1 = q3 ? t101 : t001;
        SELT(q2, m00,m01,m10,m11);
        { cpx n0 = cadd(cmul(r0,m00),cmul(r1,m10)); cpx n1 = cadd(cmul(r0,m01),cmul(r1,m11)); r0=n0; r1=n1; }
        SELT(q1, m00,m01,m10,m11);
        { cpx n0 = cadd(cmul(r0,m00),cmul(r1,m10)); cpx n1 = cadd(cmul(r0,m01),cmul(r1,m11)); r0=n0; r1=n1; }
        SELT(q0, m00,m01,m10,m11);
        { cpx n0 = cadd(cmul(r0,m00),cmul(r1,m10)); cpx n1 = cadd(cmul(r0,m01),cmul(r1,m11)); r0=n0; r1=n1; }
        u4[pat][0]=r0; u4[pat][1]=r1;
      } else if (kind == 1){
        // M4 = T^{q3} T^{q2} T^{q1} T^{q0}
        cpx M00,M01,M10,M11;
        SELT(q3, M00,M01,M10,M11);
        SELT(q2, m00,m01,m10,m11);
        { cpx N00=cadd(cmul(M00,m00),cmul(M01,m10)), N01=cadd(cmul(M00,m01),cmul(M01,m11));
          cpx N10=cadd(cmul(M10,m00),cmul(M11,m10)), N11=cadd(cmul(M10,m01),cmul(M11,m11));
          M00=N00; M01=N01; M10=N10; M11=N11; }
        SELT(q1, m00,m01,m10,m11);
        { cpx N00=cadd(cmul(M00,m00),cmul(M01,m10)), N01=cadd(cmul(M00,m01),cmul(M01,m11));
          cpx N10=cadd(cmul(M10,m00),cmul(M11,m10)), N11=cadd(cmul(M10,m01),cmul(M11,m11));
          M00=N00; M01=N01; M10=N10; M11=N11; }
        SELT(q0, m00,m01,m10,m11);
        { cpx N00=cadd(cmul(M00,m00),cmul(M01,m10)), N01=cadd(cmul(M00,m01),cmul(M01,m11));
          cpx N10=cadd(cmul(M10,m00),cmul(M11,m10)), N11=cadd(cmul(M10,m01),cmul(M11,m11));
          M00=N00; M01=N01; M10=N10; M11=N11; }
        M4p[pat][0]=M00; M4p[pat][1]=M01; M4p[pat][2]=M10; M4p[pat][3]=M11;
      } else {
        // f4: seed e(b1,b0)_y = T[b1][y][b0]; then apply T^{b2}, T^{b3} (col-vec)
        cpx v0 = q1 ? (q0 ? t101 : t100) : (q0 ? t001 : t000);
        cpx v1 = q1 ? (q0 ? t111 : t110) : (q0 ? t011 : t010);
        SELT(q2, m00,m01,m10,m11);
        { cpx n0 = cadd(cmul(m00,v0),cmul(m01,v1)); cpx n1 = cadd(cmul(m10,v0),cmul(m11,v1)); v0=n0; v1=n1; }
        SELT(q3, m00,m01,m10,m11);
        { cpx n0 = cadd(cmul(m00,v0),cmul(m01,v1)); cpx n1 = cadd(cmul(m10,v0),cmul(m11,v1)); v0=n0; v1=n1; }
        f4p[pat][0]=v0; f4p[pat][1]=v1;
      }
    }
  }
  __syncthreads();

  // ---- F: combine + coalesced store. i = (bid<<10)|(t<<2)|k ----
  unsigned bid = blockIdx.x;
  cpx r0 = u4[bid>>6][0], r1 = u4[bid>>6][1];
  {
    const cpx* Ma = M4p[(bid>>2)&15u];               // bits 15..12 (block-uniform)
    cpx n0 = cadd(cmul(r0,Ma[0]), cmul(r1,Ma[2]));
    cpx n1 = cadd(cmul(r0,Ma[1]), cmul(r1,Ma[3]));
    r0=n0; r1=n1;
  }
  {
    const cpx* Mb = M4p[((bid&3u)<<2)|((unsigned)(t>>6)&3u)];  // bits 11..8 (wave-uniform)
    cpx n0 = cadd(cmul(r0,Mb[0]), cmul(r1,Mb[2]));
    cpx n1 = cadd(cmul(r0,Mb[1]), cmul(r1,Mb[3]));
    r0=n0; r1=n1;
  }
  {
    const cpx* Mc = M4p[(t>>2)&15];                  // bits 7..4 (per-thread)
    cpx n0 = cadd(cmul(r0,Mc[0]), cmul(r1,Mc[2]));
    cpx n1 = cadd(cmul(r0,Mc[1]), cmul(r1,Mc[3]));
    r0=n0; r1=n1;
  }
  int fb = (t&3)<<2;                                 // bits 3..2 from t, 1..0 = k
  float4 res; cpx y;
  y = cadd(cmul(r0, f4p[fb  ][0]), cmul(r1, f4p[fb  ][1])); res.x = y.x*y.x + y.y*y.y;
  y = cadd(cmul(r0, f4p[fb|1][0]), cmul(r1, f4p[fb|1][1])); res.y = y.x*y.x + y.y*y.y;
  y = cadd(cmul(r0, f4p[fb|2][0]), cmul(r1, f4p[fb|2][1])); res.z = y.x*y.x + y.y*y.y;
  y = cadd(cmul(r0, f4p[fb|3][0]), cmul(r1, f4p[fb|3][1])); res.w = y.x*y.x + y.y*y.y;
  ((float4*)out)[(bid<<8) | (unsigned)t] = res;
}

extern "C" void kernel_launch(void* const* d_in, const int* in_sizes, int n_in,
                              void* d_out, int out_size, void* d_ws, size_t ws_size,
                              hipStream_t stream) {
  const float* params = (const float*)d_in[0];
  mps_fused<<<1024, 256, 0, stream>>>(params, (float*)d_out);
}